// Round 3
// baseline (12319.978 us; speedup 1.0000x reference)
//
#include <hip/hip_runtime.h>

#define T_STEPS 4096
#define HID     512
#define NCH     256
#define DIM     128
#define VOCAB   32000
#define GRU_WGS 32

// ---------- fast transcendentals (hardware v_exp_f32 path) ----------
__device__ __forceinline__ float fast_sigmoid(float x) {
  x = fminf(fmaxf(x, -30.f), 30.f);
  const float e = __expf(-x);
  return __fdividef(1.f, 1.f + e);
}
__device__ __forceinline__ float fast_tanh(float x) {
  x = fminf(fmaxf(x, -15.f), 15.f);
  const float e = __expf(2.f * x);
  return __fdividef(e - 1.f, e + 1.f);
}

// ---------- DPP 16-lane (row) sum; result valid on row-lane 0 ----------
template <int CTRL>
__device__ __forceinline__ float dpp_add(float v) {
  const int s = __builtin_amdgcn_update_dpp(0, __float_as_int(v), CTRL, 0xF, 0xF, true);
  return v + __int_as_float(s);
}
__device__ __forceinline__ float red16(float v) {
  v = dpp_add<0xB1>(v);   // quad_perm [1,0,3,2]  (xor 1)
  v = dpp_add<0x4E>(v);   // quad_perm [2,3,0,1]  (xor 2)
  v = dpp_add<0x124>(v);  // row_ror:4
  v = dpp_add<0x128>(v);  // row_ror:8
  return v;               // lane 0 of each 16-lane row holds the total
}

// ---------- LDS float-index swizzle: XOR low3 of 16B-granule index ----------
__device__ __forceinline__ int swz(int f) {
  const int G = f >> 2;
  return (((G ^ ((G >> 3) & 7)) << 2) | (f & 3));
}

// ============================ GRU ============================
// 32 WGs x 256 threads; each wave fully autonomous (no __syncthreads in loop).
// 16-lane teams per output j. Per step: wave polls 512 tagged u64 slots
// (lane q-loop over slots 64q+lane, coalesced), gates on __all, deposits h to
// a per-wave swizzled LDS buffer (wave-synchronous ds ops), dot products from
// LDS float4 reads, DPP team-reduce, fast gates, agent-scope tagged store.
__global__ __launch_bounds__(256, 1) void gru_kernel(
    const float* __restrict__ x,
    const float* __restrict__ w_ih,
    const float* __restrict__ w_hh,
    const float* __restrict__ b_ih,
    const float* __restrict__ b_hh,
    unsigned long long* hg,            // 2 * 512 tagged slots (zeroed each launch)
    float* __restrict__ evolved)       // (4096, 512)
{
  __shared__ float hs[4][HID];         // per-wave private buffers (8 KB)
  const int tid  = threadIdx.x;
  const int wave = tid >> 6;
  const int lane = tid & 63;
  const int team = lane >> 4;          // 0..3
  const int p    = lane & 15;          // k-slice index within team
  const int j    = blockIdx.x * 16 + wave * 4 + team;   // 0..511
  float* hw = hs[wave];

  // hoisted address pieces
  const int G0  = 8 * p;               // granule base for reads
  const int key = p & 7;               // read-side XOR key
  const int l2 = lane >> 2, l03 = lane & 3, l5 = lane >> 5;

  // weights rows j (r), 512+j (z), 1024+j (n), cols [32p, 32p+32), natural order
  float4 w[3][8];
#pragma unroll
  for (int d = 0; d < 3; ++d) {
    const float4* wr = reinterpret_cast<const float4*>(w_hh + (size_t)(d * HID + j) * HID);
#pragma unroll
    for (int r = 0; r < 8; ++r) w[d][r] = wr[8 * p + r];
  }
  // xp_t = xs[t]*c + b_ih  (quat input is rank-1 in the scales vector)
  float c3[3], bi3[3], bh3[3];
#pragma unroll
  for (int d = 0; d < 3; ++d) {
    int r = d * HID + j;
    c3[d]  = w_ih[r*4+0] + 0.1f*w_ih[r*4+1] + 0.01f*w_ih[r*4+2] + 0.001f*w_ih[r*4+3];
    bi3[d] = b_ih[r];
    bh3[d] = b_hh[r];
  }

  float hprev = 0.0f;  // leader lanes (p==0) carry h[j]
  for (int s = 1; s <= T_STEPS; ++s) {
    const unsigned int want = (unsigned int)(s - 1);
    const unsigned long long* rs = hg + ((s - 1) & 1) * HID;

    const float xt = x[s - 1];

    // ---- wave-autonomous poll: 8 coalesced tagged loads per lane ----
    unsigned long long v[8];
    for (;;) {
      bool ok = true;
#pragma unroll
      for (int q = 0; q < 8; ++q)
        v[q] = __hip_atomic_load(rs + 64 * q + lane, __ATOMIC_RELAXED, __HIP_MEMORY_SCOPE_AGENT);
#pragma unroll
      for (int q = 0; q < 8; ++q) ok &= ((unsigned int)(v[q] >> 32) == want);
      if (__all(ok)) break;
    }

    // ---- deposit to per-wave swizzled LDS (wave-synchronous, no barrier) ----
#pragma unroll
    for (int q = 0; q < 8; ++q) {
      const int G = 16 * q + l2;
      const int k = (2 * q + l5) & 7;
      hw[(((G ^ k) << 2) | l03)] = __uint_as_float((unsigned int)v[q]);
    }

    // ---- dot products from LDS (float4 reads, swizzled) ----
    float a0 = 0.f, a1 = 0.f, a2 = 0.f, e0 = 0.f, e1 = 0.f, e2 = 0.f;
#pragma unroll
    for (int r = 0; r < 8; ++r) {
      const float4 h4 = *reinterpret_cast<const float4*>(&hw[((G0 + r) ^ key) << 2]);
      const float4 w0 = w[0][r], w1 = w[1][r], w2 = w[2][r];
      a0 = fmaf(w0.x, h4.x, a0); e0 = fmaf(w0.y, h4.y, e0);
      a0 = fmaf(w0.z, h4.z, a0); e0 = fmaf(w0.w, h4.w, e0);
      a1 = fmaf(w1.x, h4.x, a1); e1 = fmaf(w1.y, h4.y, e1);
      a1 = fmaf(w1.z, h4.z, a1); e1 = fmaf(w1.w, h4.w, e1);
      a2 = fmaf(w2.x, h4.x, a2); e2 = fmaf(w2.y, h4.y, e2);
      a2 = fmaf(w2.z, h4.z, a2); e2 = fmaf(w2.w, h4.w, e2);
    }
    a0 += e0; a1 += e1; a2 += e2;

    // ---- DPP team reduce (VALU only) ----
    a0 = red16(a0); a1 = red16(a1); a2 = red16(a2);

    if (p == 0) {
      const float rg = fast_sigmoid(fmaf(xt, c3[0], bi3[0]) + a0 + bh3[0]);
      const float zg = fast_sigmoid(fmaf(xt, c3[1], bi3[1]) + a1 + bh3[1]);
      const float ng = fast_tanh(fmaf(xt, c3[2], bi3[2]) + rg * (a2 + bh3[2]));
      const float hn = (1.0f - zg) * ng + zg * hprev;
      hprev = hn;
      const unsigned long long pk =
          ((unsigned long long)(unsigned int)s << 32) | (unsigned long long)__float_as_uint(hn);
      __hip_atomic_store(hg + (s & 1) * HID + j, pk, __ATOMIC_RELAXED, __HIP_MEMORY_SCOPE_AGENT);
      evolved[(size_t)(s - 1) * HID + j] = hn;
    }
  }
}

// ==================== FFT -> phase filter -> IFFT ====================
__device__ __forceinline__ void fft4096(float2* buf, int tid)
{
  for (int st = 0; st < 12; ++st) {
    const int half = 1 << st;
    const float ang0 = -6.283185307179586f / (float)(2 << st);
    for (int i = tid; i < 2048; i += 256) {
      const int blk = i >> st;
      const int pos = i & (half - 1);
      const int idx = blk * (2 << st) + pos;
      float sn, cs;
      sincosf(ang0 * (float)pos, &sn, &cs);
      const float2 u = buf[idx];
      const float2 v = buf[idx + half];
      const float tr = v.x * cs - v.y * sn;
      const float ti = v.x * sn + v.y * cs;
      buf[idx]        = make_float2(u.x + tr, u.y + ti);
      buf[idx + half] = make_float2(u.x - tr, u.y - ti);
    }
    __syncthreads();
  }
}

__global__ __launch_bounds__(256) void fft_kernel(
    const float* __restrict__ evolved,   // (4096, 512)
    const float* __restrict__ alpha_p,
    float* __restrict__ ft)              // (4096, 256)
{
  __shared__ float2 buf[4096];           // 32 KB
  const int tid = threadIdx.x;
  const int c = blockIdx.x;
  const float alpha = alpha_p[0];

  for (int t = tid; t < 4096; t += 256) {
    const int r = __brev((unsigned)t) >> 20;
    buf[r] = make_float2(evolved[(size_t)t * HID + 2 * c],
                         evolved[(size_t)t * HID + 2 * c + 1]);
  }
  __syncthreads();
  fft4096(buf, tid);

  for (int t = tid; t < 4096; t += 256) {
    float2 v = buf[t];
    const float km = sqrtf(v.x * v.x + v.y * v.y) + 1e-10f;
    const float pf = alpha * atanf(logf(km));
    float sn, cs;
    sincosf(pf, &sn, &cs);
    const float rr = v.x * cs - v.y * sn;
    const float ii = v.x * sn + v.y * cs;
    buf[t] = make_float2(rr, -ii);
  }
  __syncthreads();
  for (int t = tid; t < 4096; t += 256) {
    const int r = __brev((unsigned)t) >> 20;
    if (r > t) { float2 tmp = buf[t]; buf[t] = buf[r]; buf[r] = tmp; }
  }
  __syncthreads();
  fft4096(buf, tid);

  const float inv = 1.0f / 4096.0f;
  for (int t = tid; t < 4096; t += 256) {
    ft[(size_t)t * NCH + c] = buf[t].x * inv;   // Re(ifft) = Re(fft(conj))/N
  }
}

// ==================== coh = ft @ pc_w.T + pc_b ====================
__global__ __launch_bounds__(256) void coh_kernel(
    const float* __restrict__ ft,     // (4096, 256)
    const float* __restrict__ pcw,    // (128, 256)
    const float* __restrict__ pcb,    // (128)
    float* __restrict__ x0)           // (4096, 128)
{
  __shared__ float wT[64][132];
  __shared__ float fT[64][68];
  const int tid = threadIdx.x;
  const int rg = tid >> 4;
  const int cg = tid & 15;
  const int t0 = blockIdx.x * 64;
  float acc[4][8];
#pragma unroll
  for (int i = 0; i < 4; ++i)
#pragma unroll
    for (int jj = 0; jj < 8; ++jj) acc[i][jj] = 0.f;

  for (int kt = 0; kt < 256; kt += 64) {
    __syncthreads();
    for (int u = tid; u < 64 * DIM; u += 256) {
      const int col = u >> 6, kk = u & 63;
      wT[kk][col] = pcw[col * 256 + kt + kk];
    }
    for (int u = tid; u < 64 * 64; u += 256) {
      const int row = u >> 6, kk = u & 63;
      fT[kk][row] = ft[(size_t)(t0 + row) * NCH + kt + kk];
    }
    __syncthreads();
#pragma unroll 4
    for (int k = 0; k < 64; ++k) {
      const float4 a  = *(const float4*)&fT[k][rg * 4];
      const float4 w0 = *(const float4*)&wT[k][cg * 8];
      const float4 w1 = *(const float4*)&wT[k][cg * 8 + 4];
      const float av[4] = {a.x, a.y, a.z, a.w};
      const float wv[8] = {w0.x, w0.y, w0.z, w0.w, w1.x, w1.y, w1.z, w1.w};
#pragma unroll
      for (int i = 0; i < 4; ++i)
#pragma unroll
        for (int jj = 0; jj < 8; ++jj)
          acc[i][jj] = fmaf(av[i], wv[jj], acc[i][jj]);
    }
  }
#pragma unroll
  for (int i = 0; i < 4; ++i) {
    const int t = t0 + rg * 4 + i;
#pragma unroll
    for (int jj = 0; jj < 8; ++jj)
      x0[(size_t)t * DIM + cg * 8 + jj] = acc[i][jj] + pcb[cg * 8 + jj];
  }
}

// ==================== logits = (x0@Pre.T)^2 + (x0@Pim.T)^2 ====================
__global__ __launch_bounds__(256) void logits_kernel(
    const float* __restrict__ x0,      // (4096, 128)
    const float* __restrict__ patre,   // (32000, 128)
    const float* __restrict__ patim,   // (32000, 128)
    float* __restrict__ out)           // (4096, 32000)
{
  __shared__ float aT[32][68];
  __shared__ float brT[32][132];
  __shared__ float biT[32][132];
  const int tid = threadIdx.x;
  const int tx = tid & 31;
  const int ty = tid >> 5;
  const int m0 = blockIdx.y * 64;
  const int n0 = blockIdx.x * 128;
  float accr[8][4], acci[8][4];
#pragma unroll
  for (int i = 0; i < 8; ++i)
#pragma unroll
    for (int jj = 0; jj < 4; ++jj) { accr[i][jj] = 0.f; acci[i][jj] = 0.f; }

  for (int kt = 0; kt < 128; kt += 32) {
    __syncthreads();
    for (int u = tid; u < 64 * 32; u += 256) {
      const int mm = u >> 5, kk = u & 31;
      aT[kk][mm] = x0[(size_t)(m0 + mm) * DIM + kt + kk];
    }
    for (int u = tid; u < 128 * 32; u += 256) {
      const int nn = u >> 5, kk = u & 31;
      brT[kk][nn] = patre[(size_t)(n0 + nn) * DIM + kt + kk];
      biT[kk][nn] = patim[(size_t)(n0 + nn) * DIM + kt + kk];
    }
    __syncthreads();
#pragma unroll 4
    for (int k = 0; k < 32; ++k) {
      const float4 q0 = *(const float4*)&aT[k][ty * 8];
      const float4 q1 = *(const float4*)&aT[k][ty * 8 + 4];
      const float4 br = *(const float4*)&brT[k][tx * 4];
      const float4 bi = *(const float4*)&biT[k][tx * 4];
      const float av[8]  = {q0.x, q0.y, q0.z, q0.w, q1.x, q1.y, q1.z, q1.w};
      const float brv[4] = {br.x, br.y, br.z, br.w};
      const float biv[4] = {bi.x, bi.y, bi.z, bi.w};
#pragma unroll
      for (int i = 0; i < 8; ++i)
#pragma unroll
        for (int jj = 0; jj < 4; ++jj) {
          accr[i][jj] = fmaf(av[i], brv[jj], accr[i][jj]);
          acci[i][jj] = fmaf(av[i], biv[jj], acci[i][jj]);
        }
    }
  }
#pragma unroll
  for (int i = 0; i < 8; ++i) {
    const size_t m = (size_t)(m0 + ty * 8 + i);
    float4 o;
    o.x = accr[i][0] * accr[i][0] + acci[i][0] * acci[i][0];
    o.y = accr[i][1] * accr[i][1] + acci[i][1] * acci[i][1];
    o.z = accr[i][2] * accr[i][2] + acci[i][2] * acci[i][2];
    o.w = accr[i][3] * accr[i][3] + acci[i][3] * acci[i][3];
    *(float4*)&out[m * VOCAB + n0 + tx * 4] = o;
  }
}

// ============================ launch ============================
extern "C" void kernel_launch(void* const* d_in, const int* in_sizes, int n_in,
                              void* d_out, int out_size, void* d_ws, size_t ws_size,
                              hipStream_t stream)
{
  const float* x     = (const float*)d_in[0];
  const float* w_ih  = (const float*)d_in[1];
  const float* w_hh  = (const float*)d_in[2];
  const float* b_ih  = (const float*)d_in[3];
  const float* b_hh  = (const float*)d_in[4];
  const float* alpha = (const float*)d_in[5];
  const float* pc_w  = (const float*)d_in[6];
  const float* pc_b  = (const float*)d_in[7];
  const float* patre = (const float*)d_in[8];
  const float* patim = (const float*)d_in[9];

  float* out = (float*)d_out;
  float* evolved = out;                 // 4096*512 floats (inside d_out)
  float* ft      = out + 4194304;       // 4096*256 floats

  unsigned long long* hg = (unsigned long long*)d_ws;   // 2*512 slots = 8 KB
  float* x0 = (float*)((char*)d_ws + 8192);             // 4096*128 = 2 MB

  hipMemsetAsync(d_ws, 0, 8192, stream);

  gru_kernel<<<GRU_WGS, 256, 0, stream>>>(x, w_ih, w_hh, b_ih, b_hh, hg, evolved);
  fft_kernel<<<256, 256, 0, stream>>>(evolved, alpha, ft);
  coh_kernel<<<64, 256, 0, stream>>>(ft, pc_w, pc_b, x0);
  logits_kernel<<<dim3(250, 64), 256, 0, stream>>>(x0, patre, patim, out);
}